// Round 2
// baseline (367.256 us; speedup 1.0000x reference)
//
#include <hip/hip_runtime.h>
#include <hip/hip_bf16.h>
#include <float.h>
#include <math.h>

#define N_TOK 16384
#define DIM   2048
#define NE    64
#define ROWS  128        // 64 gate rows + 64 noise rows
#define TB    64         // tokens per block
#define KT    64         // K tile (per half, per iteration)
#define KHALF 1024       // DIM/2 per K-split half
#define NKT   16         // KHALF/KT
#define KTP   68         // padded LDS leading dim: row stride = 4 banks
#define EPSF  1e-9f

// LDS float offsets
#define XS_OFF(h)   ((h) * (TB * KTP))                      // xs[2][64][KTP]
#define WS_OFF(h)   (2 * TB * KTP + (h) * (ROWS * KTP))     // wsh[2][128][KTP]
#define SM_FLOATS   (2 * TB * KTP + 2 * ROWS * KTP)         // 26112 floats = 104448 B

// ---------- wave-wide helpers (wave64) ----------
__device__ __forceinline__ float wave_sum(float v) {
#pragma unroll
    for (int d = 32; d > 0; d >>= 1) v += __shfl_xor(v, d, 64);
    return v;
}

// max with lowest-index tie-break (matches jax.lax.top_k ordering)
__device__ __forceinline__ void wave_argmax(float v, int i, float& mv, int& mi) {
    float bv = v; int bi = i;
#pragma unroll
    for (int d = 32; d > 0; d >>= 1) {
        float ov = __shfl_xor(bv, d, 64);
        int   oi = __shfl_xor(bi, d, 64);
        if (ov > bv || (ov == bv && oi < bi)) { bv = ov; bi = oi; }
    }
    mv = bv; mi = bi;
}

// ---------- fused GEMM (x @ [Wg;Wn]^T, in-block K-split) + router epilogue ----------
__global__ __launch_bounds__(256, 1) void router_kernel(
    const float* __restrict__ x,      // [N_TOK][DIM]
    const float* __restrict__ noise,  // [N_TOK][NE]
    const float* __restrict__ Wg,     // [NE][DIM]
    const float* __restrict__ Wn,     // [NE][DIM]
    float* __restrict__ out,          // topi(2N) | weights(2N) | priority(N) | aux(1)
    float* __restrict__ accum)        // ws: importance[64] | load[64]
{
    __shared__ float sm[SM_FLOATS];

    const int t   = threadIdx.x;
    const int kz  = t >> 7;          // K-half 0/1
    const int u   = t & 127;
    const int tg  = u >> 4;          // 0..7  -> tokens tg + 8i
    const int og  = u & 15;          // 0..15 -> rows   og + 16j
    const int c4  = t & 15;          // staging column (float4 index)
    const int rs  = t >> 4;          // staging row seed
    const int tokBase = blockIdx.x * TB;

    float acc[8][8];
#pragma unroll
    for (int i = 0; i < 8; ++i)
#pragma unroll
        for (int j = 0; j < 8; ++j) acc[i][j] = 0.f;

    // prefetch x tile 0 into registers (8 float4/thread covers xs[2][64][16f4])
    float4 px[8];
#pragma unroll
    for (int r = 0; r < 8; ++r) {
        int row = (rs + 16 * r) & 63;
        int h   = r >> 2;
        px[r] = *(const float4*)(x + (size_t)(tokBase + row) * DIM + h * KHALF + c4 * 4);
    }

    for (int kt = 0; kt < NKT; ++kt) {
        __syncthreads();   // previous compute finished reading LDS
        // write prefetched x regs -> LDS
#pragma unroll
        for (int r = 0; r < 8; ++r) {
            int row = (rs + 16 * r) & 63;
            int h   = r >> 2;
            *(float4*)(sm + XS_OFF(h) + row * KTP + c4 * 4) = px[r];
        }
        // JIT W loads (L2-resident) -> LDS  (16 float4/thread covers wsh[2][128][16f4])
#pragma unroll
        for (int r = 0; r < 16; ++r) {
            int wrow = (rs + 16 * r) & 127;
            int h    = r >> 3;
            const float* src = (wrow < NE) ? (Wg + (size_t)wrow * DIM)
                                           : (Wn + (size_t)(wrow - NE) * DIM);
            float4 v = *(const float4*)(src + h * KHALF + kt * KT + c4 * 4);
            *(float4*)(sm + WS_OFF(h) + wrow * KTP + c4 * 4) = v;
        }
        __syncthreads();
        // prefetch next x tile (overlaps compute below)
        if (kt < NKT - 1) {
#pragma unroll
            for (int r = 0; r < 8; ++r) {
                int row = (rs + 16 * r) & 63;
                int h   = r >> 2;
                px[r] = *(const float4*)(x + (size_t)(tokBase + row) * DIM
                                           + h * KHALF + (kt + 1) * KT + c4 * 4);
            }
        }
        // compute this K-tile from my half's buffers
        const float* xb = sm + XS_OFF(kz);
        const float* wb = sm + WS_OFF(kz);
#pragma unroll 4
        for (int kk4 = 0; kk4 < KT / 4; ++kk4) {
            float4 xv[8], wv[8];
#pragma unroll
            for (int i = 0; i < 8; ++i)
                xv[i] = *(const float4*)(xb + (tg + 8 * i) * KTP + kk4 * 4);
#pragma unroll
            for (int j = 0; j < 8; ++j)
                wv[j] = *(const float4*)(wb + (og + 16 * j) * KTP + kk4 * 4);
#pragma unroll
            for (int i = 0; i < 8; ++i)
#pragma unroll
                for (int j = 0; j < 8; ++j) {
                    acc[i][j] += xv[i].x * wv[j].x;
                    acc[i][j] += xv[i].y * wv[j].y;
                    acc[i][j] += xv[i].z * wv[j].z;
                    acc[i][j] += xv[i].w * wv[j].w;
                }
        }
    }

    // ---------- merge K-halves into logi[64][129] (aliases staging LDS) ----------
    __syncthreads();
    float* logi   = sm;                      // [64][ROWS+1]
    float* s_part = sm + TB * (ROWS + 1);    // [4][2][64]
    if (kz == 0) {
#pragma unroll
        for (int i = 0; i < 8; ++i)
#pragma unroll
            for (int j = 0; j < 8; ++j)
                logi[(tg + 8 * i) * (ROWS + 1) + og + 16 * j] = acc[i][j];
    }
    __syncthreads();
    if (kz == 1) {
#pragma unroll
        for (int i = 0; i < 8; ++i)
#pragma unroll
            for (int j = 0; j < 8; ++j)
                logi[(tg + 8 * i) * (ROWS + 1) + og + 16 * j] += acc[i][j];
    }
    __syncthreads();

    // ---------- per-token router epilogue: wave w handles 16 tokens, lane = expert ----------
    const int wv_id = t >> 6;      // 0..3
    const int lane  = t & 63;      // expert id
    float imp_acc = 0.f, load_acc = 0.f;

    for (int tt = 0; tt < TB / 4; ++tt) {
        const int tok = wv_id * (TB / 4) + tt;
        const int gt  = tokBase + tok;

        float logit = logi[tok * (ROWS + 1) + lane];
        float rawn  = logi[tok * (ROWS + 1) + NE + lane];
        // softplus (stable, matches jax.nn.softplus) + EPS
        float sp   = fmaxf(rawn, 0.f) + log1pf(expf(-fabsf(rawn)));
        float nstd = sp + EPSF;
        float nz   = noise[(size_t)gt * NE + lane];
        float noisy = logit + nz * nstd;

        // top-3 of 64 lanes
        float v0, v1, v2; int i0, i1, i2d;
        wave_argmax(noisy, lane, v0, i0);
        float m1 = (lane == i0) ? -FLT_MAX : noisy;
        wave_argmax(m1, lane, v1, i1);
        float m2 = (lane == i0 || lane == i1) ? -FLT_MAX : noisy;
        wave_argmax(m2, lane, v2, i2d);
        (void)i2d;

        // softmax over the two surviving entries (max = v0)
        float e1  = expf(v1 - v0);
        float den = 1.f + e1;
        float w0v = 1.f / den;
        float w1v = e1 / den;

        if (lane == 0) {
            out[2 * gt]                 = (float)i0;   // topi
            out[2 * gt + 1]             = (float)i1;
            out[2 * N_TOK + 2 * gt]     = w0v;         // weights
            out[2 * N_TOK + 2 * gt + 1] = w1v;
            out[4 * N_TOK + gt]         = w0v;         // priority = max weight
        }

        // importance contribution (gates_full row is zero except top-2)
        imp_acc += (lane == i0) ? w0v : ((lane == i1) ? w1v : 0.f);

        // load contribution: Phi((logits - kth_excl)/(noise_std+EPS))
        bool in_topk = (lane == i0) || (lane == i1);
        float kth = in_topk ? v2 : v1;
        float z = (logit - kth) / (nstd + EPSF);
        load_acc += 0.5f * (1.f + erff(z * 0.7071067811865476f));
    }

    s_part[(wv_id * 2 + 0) * NE + lane] = imp_acc;
    s_part[(wv_id * 2 + 1) * NE + lane] = load_acc;
    __syncthreads();

    if (t < 2 * NE) {
        int which = t >> 6, e = t & 63;
        float s = s_part[(0 * 2 + which) * NE + e] + s_part[(1 * 2 + which) * NE + e]
                + s_part[(2 * 2 + which) * NE + e] + s_part[(3 * 2 + which) * NE + e];
        atomicAdd(&accum[which * NE + e], s);
    }
}

// ---------- finalize: aux = 0.1*cv2(importance) + 0.1*cv2(load) ----------
__global__ void finalize_kernel(const float* __restrict__ accum,
                                float* __restrict__ out_aux) {
    const int lane = threadIdx.x;  // 64 threads
    float imp  = accum[lane];
    float load = accum[NE + lane];

    float m_imp = wave_sum(imp) * (1.f / NE);
    float di = imp - m_imp;
    float var_imp = wave_sum(di * di) * (1.f / NE);

    float m_load = wave_sum(load) * (1.f / NE);
    float dl = load - m_load;
    float var_load = wave_sum(dl * dl) * (1.f / NE);

    if (lane == 0) {
        out_aux[0] = 0.1f * (var_imp  / (m_imp  * m_imp  + EPSF))
                   + 0.1f * (var_load / (m_load * m_load + EPSF));
    }
}

extern "C" void kernel_launch(void* const* d_in, const int* in_sizes, int n_in,
                              void* d_out, int out_size, void* d_ws, size_t ws_size,
                              hipStream_t stream) {
    const float* x     = (const float*)d_in[0];
    const float* noise = (const float*)d_in[1];
    const float* Wg    = (const float*)d_in[2];
    const float* Wn    = (const float*)d_in[3];
    float* out   = (float*)d_out;
    float* accum = (float*)d_ws;

    hipMemsetAsync(d_ws, 0, 2 * NE * sizeof(float), stream);
    router_kernel<<<N_TOK / TB, 256, 0, stream>>>(x, noise, Wg, Wn, out, accum);
    finalize_kernel<<<1, 64, 0, stream>>>(accum, out + 5 * (size_t)N_TOK);
}